// Round 11
// baseline (715.541 us; speedup 1.0000x reference)
//
#include <hip/hip_runtime.h>
#include <hip/hip_bf16.h>
#include <math.h>

// Bahdanau attention + reservoir RNN cell.
//  K0: Ua_w f32 -> bf16 in MFMA B-fragment layout (L2-resident, read direct)
//  K1: q = h_prev@Wa^T + Wa_b + Ua_b
//  K2: PERSISTENT: 256 blocks x 1024 thr (16 waves = 4/SIMD). Block owns
//      (b, 16 chunks). Wave = 64 rows x 32 cols -> acc 4x2 = 32 AGPR.
//      __launch_bounds__(1024, 4): 4 waves/EU -> 1 block/CU -> 128 reg/wave
//      budget incl. AGPRs (gfx950 unified file). Without the 2nd arg the
//      compiler budgeted 64/wave and spilled 272 MB (R10).
//      Full 64KB bf16 A-tile, double-buffered (128KB LDS): stage tile i+1
//      (VGPR cvt + XOR-swizzled ds_write, bank-clean) interleaved with the
//      16 MFMA clusters of tile i. B-fragments direct from L2 per cluster.
//      Epilogue: tanh(q+k)·Va -> partial softmax + context from bf16 LDS.
//  K3: exact combine of 32 partials -> context
//  K4: RNN cell (grid split over o for full-chip coverage)

typedef __attribute__((ext_vector_type(8))) short short8;
typedef __attribute__((ext_vector_type(8))) unsigned short ushort8;
typedef __attribute__((ext_vector_type(4))) float f32x4;

#define S_LEN 2048
#define BDIM 128
#define HDIM 512
#define EDIM 512
#define BM 64
#define NCHUNK (S_LEN / BM)  // 32

__device__ __forceinline__ unsigned short f2bf(float f) {
  unsigned int u = __float_as_uint(f);
  u += 0x7fffu + ((u >> 16) & 1u);  // RNE
  return (unsigned short)(u >> 16);
}

__device__ __forceinline__ float bf2f(unsigned short u) {
  return __uint_as_float(((unsigned int)u) << 16);
}

__device__ __forceinline__ float fast_tanh(float x) {
  float e = __expf(2.0f * x);
  return 1.0f - 2.0f / (e + 1.0f);
}

// Ua[512][512] f32 -> bf16 fragment layout:
// tile (ct,kt): col = ct*16 + (l&15), k = kt*32 + (l>>4)*8 + e
// at dst[((ct*16+kt)*64 + l)*8 + e]
__global__ __launch_bounds__(256) void k_cvt_b(const float* __restrict__ src,
                                               unsigned short* __restrict__ dst) {
  int tid = blockIdx.x * 256 + threadIdx.x;  // 0..32767
  int ct = tid >> 10;
  int kt = (tid >> 6) & 15;
  int l = tid & 63;
  int col = ct * 16 + (l & 15);
  int k = kt * 32 + (l >> 4) * 8;
  const float4* s = (const float4*)(src + (size_t)col * HDIM + k);
  float4 v0 = s[0], v1 = s[1];
  ushort8 p;
  p[0] = f2bf(v0.x); p[1] = f2bf(v0.y); p[2] = f2bf(v0.z); p[3] = f2bf(v0.w);
  p[4] = f2bf(v1.x); p[5] = f2bf(v1.y); p[6] = f2bf(v1.z); p[7] = f2bf(v1.w);
  *(ushort8*)(dst + (size_t)tid * 8) = p;
}

__global__ __launch_bounds__(256) void k_q(const float* __restrict__ hp,
                                           const float* __restrict__ Wa,
                                           const float* __restrict__ Wab,
                                           const float* __restrict__ Uab,
                                           float* __restrict__ q) {
  int b = blockIdx.x, oh = blockIdx.y;
  int o = oh * 256 + threadIdx.x;
  __shared__ float hs[HDIM];
  hs[threadIdx.x] = hp[b * HDIM + threadIdx.x];
  hs[threadIdx.x + 256] = hp[b * HDIM + threadIdx.x + 256];
  __syncthreads();
  const float4* wr = (const float4*)(Wa + (size_t)o * HDIM);
  float acc = 0.f;
#pragma unroll 8
  for (int i = 0; i < HDIM / 4; ++i) {
    float4 v = wr[i];
    acc += v.x * hs[i * 4 + 0] + v.y * hs[i * 4 + 1] + v.z * hs[i * 4 + 2] + v.w * hs[i * 4 + 3];
  }
  q[b * HDIM + o] = acc + Wab[o] + Uab[o];
}

__global__ __launch_bounds__(1024, 4) void k_scores_ctx(
    const float* __restrict__ xref, const unsigned short* __restrict__ uab,
    const float* __restrict__ q, const float* __restrict__ va,
    float* __restrict__ mArr, float* __restrict__ lArr, float* __restrict__ cpart) {
  int p = blockIdx.x;        // 0..255
  int b = p >> 1;
  int chunk0 = (p & 1) * 16;
  int tid = threadIdx.x;
  int l = tid & 63;
  int w = tid >> 6;          // 0..15, wave owns 64 rows x 32 cols
  int c = l & 15, g4 = l >> 4;

  // bf16 tile, XOR-swizzled in 16B groups: byte(row,kbyte) = row*1024 + (kbyte ^ ((row&7)<<4))
  __shared__ __align__(16) unsigned short As[2][BM * HDIM];  // 2 x 64 KB
  __shared__ float sc[BM];
  __shared__ float pl[BM];
  __shared__ float s_ctx[HDIM];

  f32x4 acc[4][2];
#pragma unroll
  for (int m = 0; m < 4; ++m)
#pragma unroll
    for (int n = 0; n < 2; ++n) acc[m][n] = f32x4{0.f, 0.f, 0.f, 0.f};

  // staging: thread -> row = tid>>4 (64 rows), 32 f32 at k = (tid&15)*32
  int srow = tid >> 4;
  int sk = (tid & 15) * 32;
  float4 g0, g1, g2, g3;

#define ISSUE(i, part)                                                         \
  {                                                                            \
    const float4* gp_ = (const float4*)(xref +                                 \
        ((size_t)b * S_LEN + (size_t)(chunk0 + (i)) * BM + srow) * HDIM +      \
        sk + (part) * 16);                                                     \
    g0 = gp_[0]; g1 = gp_[1]; g2 = gp_[2]; g3 = gp_[3];                        \
  }

#define WRITEP(buf, part)                                                      \
  {                                                                            \
    union { __hip_bfloat162 h[4]; ushort8 s; } u0_, u1_;                       \
    u0_.h[0] = __float22bfloat162_rn(make_float2(g0.x, g0.y));                 \
    u0_.h[1] = __float22bfloat162_rn(make_float2(g0.z, g0.w));                 \
    u0_.h[2] = __float22bfloat162_rn(make_float2(g1.x, g1.y));                 \
    u0_.h[3] = __float22bfloat162_rn(make_float2(g1.z, g1.w));                 \
    u1_.h[0] = __float22bfloat162_rn(make_float2(g2.x, g2.y));                 \
    u1_.h[1] = __float22bfloat162_rn(make_float2(g2.z, g2.w));                 \
    u1_.h[2] = __float22bfloat162_rn(make_float2(g3.x, g3.y));                 \
    u1_.h[3] = __float22bfloat162_rn(make_float2(g3.z, g3.w));                 \
    int byte0_ = (tid & 15) * 64 + (part) * 32;                                \
    char* base_ = (char*)&As[buf][0] + srow * 1024;                            \
    *(ushort8*)(base_ + ((byte0_) ^ ((srow & 7) << 4))) = u0_.s;               \
    *(ushort8*)(base_ + ((byte0_ + 16) ^ ((srow & 7) << 4))) = u1_.s;          \
  }

#define CLUSTER(buf, kt)                                                       \
  {                                                                            \
    short8 afr_[4], bfr_[2];                                                   \
    _Pragma("unroll")                                                          \
    for (int n = 0; n < 2; ++n) {                                              \
      int ct = w * 2 + n;                                                      \
      bfr_[n] = *(const short8*)(uab + (((size_t)(ct * 16 + (kt)) * 64 + l) * 8)); \
    }                                                                          \
    _Pragma("unroll")                                                          \
    for (int m = 0; m < 4; ++m) {                                              \
      int row = m * 16 + (l & 15);                                             \
      int kb = ((kt) * 64 + (l >> 4) * 16) ^ ((row & 7) << 4);                 \
      afr_[m] = *(const short8*)((const char*)&As[buf][0] + row * 1024 + kb);  \
    }                                                                          \
    __builtin_amdgcn_s_setprio(1);                                             \
    _Pragma("unroll")                                                          \
    for (int m = 0; m < 4; ++m)                                                \
      _Pragma("unroll")                                                        \
      for (int n = 0; n < 2; ++n)                                              \
        acc[m][n] = __builtin_amdgcn_mfma_f32_16x16x32_bf16(afr_[m], bfr_[n],  \
                                                            acc[m][n], 0, 0, 0); \
    __builtin_amdgcn_s_setprio(0);                                             \
  }

  // per-wave q/Va (constant over the block's 16 tiles)
  float qf[2], vf[2];
#pragma unroll
  for (int n = 0; n < 2; ++n) {
    int o = w * 32 + n * 16 + c;
    qf[n] = q[b * HDIM + o];
    vf[n] = va[o];
  }

  // prologue: stage tile 0 into buf 0
  ISSUE(0, 0); WRITEP(0, 0);
  ISSUE(0, 1); WRITEP(0, 1);
  if (tid < BM) sc[tid] = 0.f;
  __syncthreads();

  for (int i = 0; i < 16; ++i) {
    int cur = i & 1, nxt = cur ^ 1;
    int chunk = chunk0 + i;

    if (i < 15) ISSUE(i + 1, 0);
    CLUSTER(cur, 0)  CLUSTER(cur, 1)  CLUSTER(cur, 2)  CLUSTER(cur, 3)
    CLUSTER(cur, 4)  CLUSTER(cur, 5)  CLUSTER(cur, 6)  CLUSTER(cur, 7)
    if (i < 15) { WRITEP(nxt, 0); ISSUE(i + 1, 1); }
    CLUSTER(cur, 8)  CLUSTER(cur, 9)  CLUSTER(cur, 10) CLUSTER(cur, 11)
    CLUSTER(cur, 12) CLUSTER(cur, 13) CLUSTER(cur, 14) CLUSTER(cur, 15)
    if (i < 15) WRITEP(nxt, 1);

    // scores[row] += sum_o tanh(acc + q[o]) * Va[o]   (16 waves per row)
#pragma unroll
    for (int m = 0; m < 4; ++m) {
#pragma unroll
      for (int r = 0; r < 4; ++r) {
        float sum = 0.f;
#pragma unroll
        for (int n = 0; n < 2; ++n) sum += fast_tanh(acc[m][n][r] + qf[n]) * vf[n];
        sum += __shfl_xor(sum, 1);
        sum += __shfl_xor(sum, 2);
        sum += __shfl_xor(sum, 4);
        sum += __shfl_xor(sum, 8);
        if (c == 0) atomicAdd(&sc[m * 16 + g4 * 4 + r], sum);
      }
    }
    __syncthreads();

    // softmax over the 64 local rows (each wave computes identically)
    float M = sc[l];
#pragma unroll
    for (int off = 32; off >= 1; off >>= 1) M = fmaxf(M, __shfl_xor(M, off));
    float pp = __expf(sc[l] - M);
    float lsum = pp;
#pragma unroll
    for (int off = 32; off >= 1; off >>= 1) lsum += __shfl_xor(lsum, off);
    if (w == 0) pl[l] = pp;
    if (tid == 0) {
      mArr[b * NCHUNK + chunk] = M;
      lArr[b * NCHUNK + chunk] = lsum;
    }
    __syncthreads();
    if (tid < BM) sc[tid] = 0.f;  // for next tile (used only after tile barrier)

    // partial context from the bf16 LDS tile; rows split across thread halves
    {
      int half = tid >> 9, h = tid & 511;
      const char* base_ = (const char*)&As[cur][0];
      float cacc = 0.f;
#pragma unroll 8
      for (int rr = 0; rr < 32; ++rr) {
        int r = half * 32 + rr;
        int byte = r * 1024 + ((h * 2) ^ ((r & 7) << 4));
        cacc += pl[r] * bf2f(*(const unsigned short*)(base_ + byte));
      }
      if (half == 0) s_ctx[h] = cacc;
      __syncthreads();
      if (half == 1)
        cpart[((size_t)b * NCHUNK + chunk) * HDIM + h] = s_ctx[h] + cacc;
    }

    // zero acc for next tile
#pragma unroll
    for (int m = 0; m < 4; ++m)
#pragma unroll
      for (int n = 0; n < 2; ++n) acc[m][n] = f32x4{0.f, 0.f, 0.f, 0.f};

    __syncthreads();  // tile boundary: nxt writes done, cur reads done
  }
#undef ISSUE
#undef WRITEP
#undef CLUSTER
}

__global__ __launch_bounds__(512) void k_combine(const float* __restrict__ mArr,
                                                 const float* __restrict__ lArr,
                                                 const float* __restrict__ cpart,
                                                 float* __restrict__ ctx,
                                                 float* __restrict__ out_ctx) {
  int b = blockIdx.x, t = threadIdx.x;
  __shared__ float wf[NCHUNK];
  __shared__ float dinv;
  if (t == 0) {
    float M = mArr[b * NCHUNK];
    for (int i = 1; i < NCHUNK; ++i) M = fmaxf(M, mArr[b * NCHUNK + i]);
    float den = 0.f;
    for (int i = 0; i < NCHUNK; ++i) {
      float f = __expf(mArr[b * NCHUNK + i] - M);
      wf[i] = f;
      den += f * lArr[b * NCHUNK + i];
    }
    dinv = 1.0f / den;
  }
  __syncthreads();
  float s = 0.f;
#pragma unroll
  for (int i = 0; i < NCHUNK; ++i) s += wf[i] * cpart[((size_t)b * NCHUNK + i) * HDIM + t];
  float c = s * dinv;
  ctx[b * HDIM + t] = c;
  out_ctx[b * HDIM + t] = c;
}

__global__ __launch_bounds__(256) void k_rnn(const float* __restrict__ xt,
                                             const float* __restrict__ ctx,
                                             const float* __restrict__ hp,
                                             const float* __restrict__ Wih,
                                             const float* __restrict__ Wihb,
                                             const float* __restrict__ Whh,
                                             const float* __restrict__ Whhb,
                                             float* __restrict__ hout) {
  int b = blockIdx.x, oh = blockIdx.y;
  int o = oh * 256 + threadIdx.x;
  __shared__ float xs[EDIM], cs[HDIM], hs[HDIM];
  xs[threadIdx.x] = xt[b * EDIM + threadIdx.x];
  xs[threadIdx.x + 256] = xt[b * EDIM + threadIdx.x + 256];
  cs[threadIdx.x] = ctx[b * HDIM + threadIdx.x];
  cs[threadIdx.x + 256] = ctx[b * HDIM + threadIdx.x + 256];
  hs[threadIdx.x] = hp[b * HDIM + threadIdx.x];
  hs[threadIdx.x + 256] = hp[b * HDIM + threadIdx.x + 256];
  __syncthreads();
  const float4* wi = (const float4*)(Wih + (size_t)o * (EDIM + HDIM));
  float acc = Wihb[o] + Whhb[o];
#pragma unroll 8
  for (int i = 0; i < EDIM / 4; ++i) {
    float4 v = wi[i];
    acc += v.x * xs[i * 4] + v.y * xs[i * 4 + 1] + v.z * xs[i * 4 + 2] + v.w * xs[i * 4 + 3];
  }
  const float4* wi2 = wi + EDIM / 4;
#pragma unroll 8
  for (int i = 0; i < HDIM / 4; ++i) {
    float4 v = wi2[i];
    acc += v.x * cs[i * 4] + v.y * cs[i * 4 + 1] + v.z * cs[i * 4 + 2] + v.w * cs[i * 4 + 3];
  }
  const float4* wh = (const float4*)(Whh + (size_t)o * HDIM);
#pragma unroll 8
  for (int i = 0; i < HDIM / 4; ++i) {
    float4 v = wh[i];
    acc += v.x * hs[i * 4] + v.y * hs[i * 4 + 1] + v.z * hs[i * 4 + 2] + v.w * hs[i * 4 + 3];
  }
  hout[b * HDIM + o] = tanhf(acc);
}

extern "C" void kernel_launch(void* const* d_in, const int* in_sizes, int n_in,
                              void* d_out, int out_size, void* d_ws, size_t ws_size,
                              hipStream_t stream) {
  const float* x_t    = (const float*)d_in[0];
  const float* x_ref  = (const float*)d_in[1];
  const float* h_prev = (const float*)d_in[2];
  const float* Wa_w   = (const float*)d_in[3];
  const float* Wa_b   = (const float*)d_in[4];
  const float* Ua_w   = (const float*)d_in[5];
  const float* Ua_b   = (const float*)d_in[6];
  const float* Va_w   = (const float*)d_in[7];
  // d_in[8] = Va_b: softmax-invariant, skipped.
  const float* Wih_w  = (const float*)d_in[9];
  const float* Wih_b  = (const float*)d_in[10];
  const float* Whh_w  = (const float*)d_in[11];
  const float* Whh_b  = (const float*)d_in[12];

  char* ws = (char*)d_ws;
  unsigned short* ua_fr = (unsigned short*)ws;   // 512 KB fragment-layout Ua
  float* q     = (float*)(ws + 524288);          // 256 KB
  float* mArr  = (float*)(ws + 786432);          // 16 KB
  float* lArr  = (float*)(ws + 802816);          // 16 KB
  float* cpart = (float*)(ws + 819200);          // 8 MB
  float* ctx   = (float*)(ws + 9207808);         // 256 KB

  float* h_out   = (float*)d_out;
  float* ctx_out = h_out + BDIM * HDIM;

  k_cvt_b<<<dim3(128), dim3(256), 0, stream>>>(Ua_w, ua_fr);
  k_q<<<dim3(BDIM, 2), dim3(256), 0, stream>>>(h_prev, Wa_w, Wa_b, Ua_b, q);
  k_scores_ctx<<<dim3(256), dim3(1024), 0, stream>>>(x_ref, ua_fr, q, Va_w, mArr, lArr, cpart);
  k_combine<<<dim3(BDIM), dim3(512), 0, stream>>>(mArr, lArr, cpart, ctx, ctx_out);
  k_rnn<<<dim3(BDIM, 2), dim3(256), 0, stream>>>(x_t, ctx, h_prev, Wih_w, Wih_b, Whh_w, Whh_b, h_out);
}

// Round 13
// 350.428 us; speedup vs baseline: 2.0419x; 2.0419x over previous
//
#include <hip/hip_runtime.h>
#include <hip/hip_bf16.h>
#include <math.h>

// Bahdanau attention + reservoir RNN cell.
//  K0: Ua_w f32 -> bf16 in MFMA B-fragment layout (L2-resident, read direct)
//  K1: q = h_prev@Wa^T + Wa_b + Ua_b
//  K2: per (b, 64-row chunk): 512 thr / 8 waves, __launch_bounds__(512,4)
//      -> 128 reg/wave budget (gfx950 unified file: arch + acc AGPRs).
//      acc = 4x2 = 32 AGPR; the 512 output cols are covered by TWO column
//      passes (8 waves x 32 cols each) over one 64KB bf16 LDS A-tile.
//      (1024-thr blocks are dead: compiler pins them at 64 VGPR and spills
//      ~272MB — R6/R10/R11.) Staging: hand-pipelined f32 loads -> cvt_pk ->
//      XOR-swizzled ds_write_b128 (uniform-octet, conflict-free both sides).
//      B-fragments direct from L2 per cluster. Epilogue per pass:
//      tanh(q+k)·Va partial sums into sc[]; then softmax + context from LDS.
//  K3: exact combine of 32 partials -> context
//  K4: RNN cell (grid split over o for full-chip coverage)

typedef __attribute__((ext_vector_type(8))) short short8;
typedef __attribute__((ext_vector_type(8))) unsigned short ushort8;
typedef __attribute__((ext_vector_type(4))) float f32x4;

#define S_LEN 2048
#define BDIM 128
#define HDIM 512
#define EDIM 512
#define BM 64
#define NCHUNK (S_LEN / BM)  // 32

__device__ __forceinline__ unsigned short f2bf(float f) {
  unsigned int u = __float_as_uint(f);
  u += 0x7fffu + ((u >> 16) & 1u);  // RNE
  return (unsigned short)(u >> 16);
}

__device__ __forceinline__ float bf2f(unsigned short u) {
  return __uint_as_float(((unsigned int)u) << 16);
}

__device__ __forceinline__ float fast_tanh(float x) {
  float e = __expf(2.0f * x);
  return 1.0f - 2.0f / (e + 1.0f);
}

// Ua[512][512] f32 -> bf16 fragment layout:
// tile (ct,kt): col = ct*16 + (l&15), k = kt*32 + (l>>4)*8 + e
// at dst[((ct*16+kt)*64 + l)*8 + e]
__global__ __launch_bounds__(256) void k_cvt_b(const float* __restrict__ src,
                                               unsigned short* __restrict__ dst) {
  int tid = blockIdx.x * 256 + threadIdx.x;  // 0..32767
  int ct = tid >> 10;
  int kt = (tid >> 6) & 15;
  int l = tid & 63;
  int col = ct * 16 + (l & 15);
  int k = kt * 32 + (l >> 4) * 8;
  const float4* s = (const float4*)(src + (size_t)col * HDIM + k);
  float4 v0 = s[0], v1 = s[1];
  ushort8 p;
  p[0] = f2bf(v0.x); p[1] = f2bf(v0.y); p[2] = f2bf(v0.z); p[3] = f2bf(v0.w);
  p[4] = f2bf(v1.x); p[5] = f2bf(v1.y); p[6] = f2bf(v1.z); p[7] = f2bf(v1.w);
  *(ushort8*)(dst + (size_t)tid * 8) = p;
}

__global__ __launch_bounds__(256) void k_q(const float* __restrict__ hp,
                                           const float* __restrict__ Wa,
                                           const float* __restrict__ Wab,
                                           const float* __restrict__ Uab,
                                           float* __restrict__ q) {
  int b = blockIdx.x, oh = blockIdx.y;
  int o = oh * 256 + threadIdx.x;
  __shared__ float hs[HDIM];
  hs[threadIdx.x] = hp[b * HDIM + threadIdx.x];
  hs[threadIdx.x + 256] = hp[b * HDIM + threadIdx.x + 256];
  __syncthreads();
  const float4* wr = (const float4*)(Wa + (size_t)o * HDIM);
  float acc = 0.f;
#pragma unroll 8
  for (int i = 0; i < HDIM / 4; ++i) {
    float4 v = wr[i];
    acc += v.x * hs[i * 4 + 0] + v.y * hs[i * 4 + 1] + v.z * hs[i * 4 + 2] + v.w * hs[i * 4 + 3];
  }
  q[b * HDIM + o] = acc + Wab[o] + Uab[o];
}

__global__ __launch_bounds__(512, 4) void k_scores_ctx(
    const float* __restrict__ xref, const unsigned short* __restrict__ uab,
    const float* __restrict__ q, const float* __restrict__ va,
    float* __restrict__ mArr, float* __restrict__ lArr, float* __restrict__ cpart) {
  int chunk = blockIdx.x;
  int b = blockIdx.y;
  int tid = threadIdx.x;
  int l = tid & 63;
  int w = tid >> 6;          // 0..7; per pass the wave owns 32 cols
  int c = l & 15, g4 = l >> 4;

  // bf16 tile, XOR-swizzled: byte(row,kbyte) = row*1024 + (kbyte ^ ((row&7)<<4))
  __shared__ __align__(16) unsigned short As[BM * HDIM];  // 64 KB
  __shared__ float sc[BM];
  __shared__ float pl[BM];

  f32x4 acc[4][2];
#pragma unroll
  for (int m = 0; m < 4; ++m)
#pragma unroll
    for (int n = 0; n < 2; ++n) acc[m][n] = f32x4{0.f, 0.f, 0.f, 0.f};

  const float* xb = xref + ((size_t)b * S_LEN + (size_t)chunk * BM) * HDIM;

  // staging: thread -> row = tid>>3 (64 rows), 64 f32 at k = (tid&7)*64
  int srow = tid >> 3;
  int sk8 = (tid & 7) * 64;
  int sw = (srow & 7) << 4;
  char* wbase = (char*)&As[0] + srow * 1024;
  float4 ga0, ga1, ga2, ga3, gb0, gb1, gb2, gb3;

#define ISSUE(v0, v1, v2, v3, call)                                            \
  {                                                                            \
    const float4* gp_ = (const float4*)(xb + (size_t)srow * HDIM + sk8 + (call) * 16); \
    v0 = gp_[0]; v1 = gp_[1]; v2 = gp_[2]; v3 = gp_[3];                        \
  }

#define WRITE(v0, v1, v2, v3, call)                                            \
  {                                                                            \
    union { __hip_bfloat162 h[4]; ushort8 s; } u0_, u1_;                       \
    u0_.h[0] = __float22bfloat162_rn(make_float2(v0.x, v0.y));                 \
    u0_.h[1] = __float22bfloat162_rn(make_float2(v0.z, v0.w));                 \
    u0_.h[2] = __float22bfloat162_rn(make_float2(v1.x, v1.y));                 \
    u0_.h[3] = __float22bfloat162_rn(make_float2(v1.z, v1.w));                 \
    u1_.h[0] = __float22bfloat162_rn(make_float2(v2.x, v2.y));                 \
    u1_.h[1] = __float22bfloat162_rn(make_float2(v2.z, v2.w));                 \
    u1_.h[2] = __float22bfloat162_rn(make_float2(v3.x, v3.y));                 \
    u1_.h[3] = __float22bfloat162_rn(make_float2(v3.z, v3.w));                 \
    int kb0_ = (tid & 7) * 128 + (call) * 32;                                  \
    *(ushort8*)(wbase + (kb0_ ^ sw)) = u0_.s;                                  \
    *(ushort8*)(wbase + ((kb0_ + 16) ^ sw)) = u1_.s;                           \
  }

  // 8-MFMA cluster for pass h, k-tile kt
#define CLUSTER(h, kt)                                                         \
  {                                                                            \
    short8 afr_[4], bfr_[2];                                                   \
    _Pragma("unroll")                                                          \
    for (int n = 0; n < 2; ++n) {                                              \
      int ct = (h) * 16 + w * 2 + n;                                           \
      bfr_[n] = *(const short8*)(uab + (((size_t)(ct * 16 + (kt)) * 64 + l) * 8)); \
    }                                                                          \
    _Pragma("unroll")                                                          \
    for (int m = 0; m < 4; ++m) {                                              \
      int row = m * 16 + (l & 15);                                             \
      int kb = ((kt) * 64 + (l >> 4) * 16) ^ ((row & 7) << 4);                 \
      afr_[m] = *(const short8*)((const char*)&As[0] + row * 1024 + kb);       \
    }                                                                          \
    __builtin_amdgcn_s_setprio(1);                                             \
    _Pragma("unroll")                                                          \
    for (int m = 0; m < 4; ++m)                                                \
      _Pragma("unroll")                                                        \
      for (int n = 0; n < 2; ++n)                                              \
        acc[m][n] = __builtin_amdgcn_mfma_f32_16x16x32_bf16(afr_[m], bfr_[n],  \
                                                            acc[m][n], 0, 0, 0); \
    __builtin_amdgcn_s_setprio(0);                                             \
  }

#define EPILOGUE(qf0_, qf1_, vf0_, vf1_)                                       \
  {                                                                            \
    _Pragma("unroll")                                                          \
    for (int m = 0; m < 4; ++m) {                                              \
      _Pragma("unroll")                                                        \
      for (int r = 0; r < 4; ++r) {                                            \
        float sum = fast_tanh(acc[m][0][r] + qf0_) * vf0_ +                    \
                    fast_tanh(acc[m][1][r] + qf1_) * vf1_;                     \
        sum += __shfl_xor(sum, 1);                                             \
        sum += __shfl_xor(sum, 2);                                             \
        sum += __shfl_xor(sum, 4);                                             \
        sum += __shfl_xor(sum, 8);                                             \
        if (c == 0) atomicAdd(&sc[m * 16 + g4 * 4 + r], sum);                  \
      }                                                                        \
    }                                                                          \
  }

  // stage the full 64x512 tile (hand-pipelined), zero sc, one barrier
  ISSUE(ga0, ga1, ga2, ga3, 0); ISSUE(gb0, gb1, gb2, gb3, 1);
  WRITE(ga0, ga1, ga2, ga3, 0); ISSUE(ga0, ga1, ga2, ga3, 2);
  WRITE(gb0, gb1, gb2, gb3, 1); ISSUE(gb0, gb1, gb2, gb3, 3);
  WRITE(ga0, ga1, ga2, ga3, 2); WRITE(gb0, gb1, gb2, gb3, 3);
  if (tid < BM) sc[tid] = 0.f;
  __syncthreads();

  // ---- pass 0: cols 0..255 ----
  {
    int o0 = w * 32 + c, o1 = w * 32 + 16 + c;
    float qf0 = q[b * HDIM + o0], qf1 = q[b * HDIM + o1];
    float vf0 = va[o0], vf1 = va[o1];
    CLUSTER(0, 0)  CLUSTER(0, 1)  CLUSTER(0, 2)  CLUSTER(0, 3)
    CLUSTER(0, 4)  CLUSTER(0, 5)  CLUSTER(0, 6)  CLUSTER(0, 7)
    CLUSTER(0, 8)  CLUSTER(0, 9)  CLUSTER(0, 10) CLUSTER(0, 11)
    CLUSTER(0, 12) CLUSTER(0, 13) CLUSTER(0, 14) CLUSTER(0, 15)
    EPILOGUE(qf0, qf1, vf0, vf1)
  }

#pragma unroll
  for (int m = 0; m < 4; ++m)
#pragma unroll
    for (int n = 0; n < 2; ++n) acc[m][n] = f32x4{0.f, 0.f, 0.f, 0.f};

  // ---- pass 1: cols 256..511 ----
  {
    int o0 = 256 + w * 32 + c, o1 = 256 + w * 32 + 16 + c;
    float qf0 = q[b * HDIM + o0], qf1 = q[b * HDIM + o1];
    float vf0 = va[o0], vf1 = va[o1];
    CLUSTER(1, 0)  CLUSTER(1, 1)  CLUSTER(1, 2)  CLUSTER(1, 3)
    CLUSTER(1, 4)  CLUSTER(1, 5)  CLUSTER(1, 6)  CLUSTER(1, 7)
    CLUSTER(1, 8)  CLUSTER(1, 9)  CLUSTER(1, 10) CLUSTER(1, 11)
    CLUSTER(1, 12) CLUSTER(1, 13) CLUSTER(1, 14) CLUSTER(1, 15)
    EPILOGUE(qf0, qf1, vf0, vf1)
  }
  __syncthreads();

  // softmax over the 64 local rows (each wave computes identically)
  float M = sc[l];
#pragma unroll
  for (int off = 32; off >= 1; off >>= 1) M = fmaxf(M, __shfl_xor(M, off));
  float pp = __expf(sc[l] - M);
  float lsum = pp;
#pragma unroll
  for (int off = 32; off >= 1; off >>= 1) lsum += __shfl_xor(lsum, off);
  if (tid < BM) pl[tid] = pp;
  if (tid == 0) {
    mArr[b * NCHUNK + chunk] = M;
    lArr[b * NCHUNK + chunk] = lsum;
  }
  __syncthreads();

  // partial context from the bf16 LDS tile: thread = one of 512 cols
  {
    int h2 = tid * 2;  // kbyte of this col
    const char* base_ = (const char*)&As[0];
    float cacc = 0.f;
#pragma unroll 8
    for (int r = 0; r < BM; ++r) {
      int byte = r * 1024 + (h2 ^ ((r & 7) << 4));
      cacc += pl[r] * bf2f(*(const unsigned short*)(base_ + byte));
    }
    cpart[((size_t)b * NCHUNK + chunk) * HDIM + tid] = cacc;
  }
#undef ISSUE
#undef WRITE
#undef CLUSTER
#undef EPILOGUE
}

__global__ __launch_bounds__(512) void k_combine(const float* __restrict__ mArr,
                                                 const float* __restrict__ lArr,
                                                 const float* __restrict__ cpart,
                                                 float* __restrict__ ctx,
                                                 float* __restrict__ out_ctx) {
  int b = blockIdx.x, t = threadIdx.x;
  __shared__ float wf[NCHUNK];
  __shared__ float dinv;
  if (t == 0) {
    float M = mArr[b * NCHUNK];
    for (int i = 1; i < NCHUNK; ++i) M = fmaxf(M, mArr[b * NCHUNK + i]);
    float den = 0.f;
    for (int i = 0; i < NCHUNK; ++i) {
      float f = __expf(mArr[b * NCHUNK + i] - M);
      wf[i] = f;
      den += f * lArr[b * NCHUNK + i];
    }
    dinv = 1.0f / den;
  }
  __syncthreads();
  float s = 0.f;
#pragma unroll
  for (int i = 0; i < NCHUNK; ++i) s += wf[i] * cpart[((size_t)b * NCHUNK + i) * HDIM + t];
  float c = s * dinv;
  ctx[b * HDIM + t] = c;
  out_ctx[b * HDIM + t] = c;
}

__global__ __launch_bounds__(256) void k_rnn(const float* __restrict__ xt,
                                             const float* __restrict__ ctx,
                                             const float* __restrict__ hp,
                                             const float* __restrict__ Wih,
                                             const float* __restrict__ Wihb,
                                             const float* __restrict__ Whh,
                                             const float* __restrict__ Whhb,
                                             float* __restrict__ hout) {
  int b = blockIdx.x, oh = blockIdx.y;
  int o = oh * 256 + threadIdx.x;
  __shared__ float xs[EDIM], cs[HDIM], hs[HDIM];
  xs[threadIdx.x] = xt[b * EDIM + threadIdx.x];
  xs[threadIdx.x + 256] = xt[b * EDIM + threadIdx.x + 256];
  cs[threadIdx.x] = ctx[b * HDIM + threadIdx.x];
  cs[threadIdx.x + 256] = ctx[b * HDIM + threadIdx.x + 256];
  hs[threadIdx.x] = hp[b * HDIM + threadIdx.x];
  hs[threadIdx.x + 256] = hp[b * HDIM + threadIdx.x + 256];
  __syncthreads();
  const float4* wi = (const float4*)(Wih + (size_t)o * (EDIM + HDIM));
  float acc = Wihb[o] + Whhb[o];
#pragma unroll 8
  for (int i = 0; i < EDIM / 4; ++i) {
    float4 v = wi[i];
    acc += v.x * xs[i * 4] + v.y * xs[i * 4 + 1] + v.z * xs[i * 4 + 2] + v.w * xs[i * 4 + 3];
  }
  const float4* wi2 = wi + EDIM / 4;
#pragma unroll 8
  for (int i = 0; i < HDIM / 4; ++i) {
    float4 v = wi2[i];
    acc += v.x * cs[i * 4] + v.y * cs[i * 4 + 1] + v.z * cs[i * 4 + 2] + v.w * cs[i * 4 + 3];
  }
  const float4* wh = (const float4*)(Whh + (size_t)o * HDIM);
#pragma unroll 8
  for (int i = 0; i < HDIM / 4; ++i) {
    float4 v = wh[i];
    acc += v.x * hs[i * 4] + v.y * hs[i * 4 + 1] + v.z * hs[i * 4 + 2] + v.w * hs[i * 4 + 3];
  }
  hout[b * HDIM + o] = tanhf(acc);
}

extern "C" void kernel_launch(void* const* d_in, const int* in_sizes, int n_in,
                              void* d_out, int out_size, void* d_ws, size_t ws_size,
                              hipStream_t stream) {
  const float* x_t    = (const float*)d_in[0];
  const float* x_ref  = (const float*)d_in[1];
  const float* h_prev = (const float*)d_in[2];
  const float* Wa_w   = (const float*)d_in[3];
  const float* Wa_b   = (const float*)d_in[4];
  const float* Ua_w   = (const float*)d_in[5];
  const float* Ua_b   = (const float*)d_in[6];
  const float* Va_w   = (const float*)d_in[7];
  // d_in[8] = Va_b: softmax-invariant, skipped.
  const float* Wih_w  = (const float*)d_in[9];
  const float* Wih_b  = (const float*)d_in[10];
  const float* Whh_w  = (const float*)d_in[11];
  const float* Whh_b  = (const float*)d_in[12];

  char* ws = (char*)d_ws;
  unsigned short* ua_fr = (unsigned short*)ws;   // 512 KB fragment-layout Ua
  float* q     = (float*)(ws + 524288);          // 256 KB
  float* mArr  = (float*)(ws + 786432);          // 16 KB
  float* lArr  = (float*)(ws + 802816);          // 16 KB
  float* cpart = (float*)(ws + 819200);          // 8 MB
  float* ctx   = (float*)(ws + 9207808);         // 256 KB

  float* h_out   = (float*)d_out;
  float* ctx_out = h_out + BDIM * HDIM;

  k_cvt_b<<<dim3(128), dim3(256), 0, stream>>>(Ua_w, ua_fr);
  k_q<<<dim3(BDIM, 2), dim3(256), 0, stream>>>(h_prev, Wa_w, Wa_b, Ua_b, q);
  k_scores_ctx<<<dim3(NCHUNK, BDIM), dim3(512), 0, stream>>>(x_ref, ua_fr, q, Va_w, mArr, lArr, cpart);
  k_combine<<<dim3(BDIM), dim3(512), 0, stream>>>(mArr, lArr, cpart, ctx, ctx_out);
  k_rnn<<<dim3(BDIM, 2), dim3(256), 0, stream>>>(x_t, ctx, h_prev, Wih_w, Wih_b, Whh_w, Whh_b, h_out);
}

// Round 14
// 294.896 us; speedup vs baseline: 2.4264x; 1.1883x over previous
//
#include <hip/hip_runtime.h>
#include <hip/hip_bf16.h>
#include <math.h>

// Bahdanau attention + reservoir RNN cell.
//  K0: Ua_w f32 -> bf16 in MFMA B-fragment layout (L2-resident, read direct)
//  K1: q = h_prev@Wa^T + Wa_b + Ua_b
//  K2: per (b, 64-row chunk): 512 thr / 8 waves, (512,4) -> 2 blocks/CU,
//      4 waves/SIMD. Wave covers 64 rows x 64 cols in ONE pass: acc 4x4 =
//      64 AGPR (+ ~64 arch = 128 budget). 16-MFMA clusters x 4 waves/SIMD
//      = ~310 cy MFMA issue per L2-latency window (R7=R13=155 cy -> 17%
//      MfmaUtil invariant; this doubles it). Staging write assignment is
//      slot-bijective per consecutive-8-lane group (R13's was 8-way
//      conflicted: kb0=(tid&7)*128 vanished mod 128). Logical LDS layout,
//      cluster reads, softmax, context = R13 verbatim.
//  K3: exact combine of 32 partials -> context
//  K4: RNN cell (grid split over o for full-chip coverage)

typedef __attribute__((ext_vector_type(8))) short short8;
typedef __attribute__((ext_vector_type(8))) unsigned short ushort8;
typedef __attribute__((ext_vector_type(4))) float f32x4;

#define S_LEN 2048
#define BDIM 128
#define HDIM 512
#define EDIM 512
#define BM 64
#define NCHUNK (S_LEN / BM)  // 32

__device__ __forceinline__ unsigned short f2bf(float f) {
  unsigned int u = __float_as_uint(f);
  u += 0x7fffu + ((u >> 16) & 1u);  // RNE
  return (unsigned short)(u >> 16);
}

__device__ __forceinline__ float bf2f(unsigned short u) {
  return __uint_as_float(((unsigned int)u) << 16);
}

__device__ __forceinline__ float fast_tanh(float x) {
  float e = __expf(2.0f * x);
  return 1.0f - 2.0f / (e + 1.0f);
}

// Ua[512][512] f32 -> bf16 fragment layout:
// tile (ct,kt): col = ct*16 + (l&15), k = kt*32 + (l>>4)*8 + e
// at dst[((ct*16+kt)*64 + l)*8 + e]
__global__ __launch_bounds__(256) void k_cvt_b(const float* __restrict__ src,
                                               unsigned short* __restrict__ dst) {
  int tid = blockIdx.x * 256 + threadIdx.x;  // 0..32767
  int ct = tid >> 10;
  int kt = (tid >> 6) & 15;
  int l = tid & 63;
  int col = ct * 16 + (l & 15);
  int k = kt * 32 + (l >> 4) * 8;
  const float4* s = (const float4*)(src + (size_t)col * HDIM + k);
  float4 v0 = s[0], v1 = s[1];
  ushort8 p;
  p[0] = f2bf(v0.x); p[1] = f2bf(v0.y); p[2] = f2bf(v0.z); p[3] = f2bf(v0.w);
  p[4] = f2bf(v1.x); p[5] = f2bf(v1.y); p[6] = f2bf(v1.z); p[7] = f2bf(v1.w);
  *(ushort8*)(dst + (size_t)tid * 8) = p;
}

__global__ __launch_bounds__(256) void k_q(const float* __restrict__ hp,
                                           const float* __restrict__ Wa,
                                           const float* __restrict__ Wab,
                                           const float* __restrict__ Uab,
                                           float* __restrict__ q) {
  int b = blockIdx.x, oh = blockIdx.y;
  int o = oh * 256 + threadIdx.x;
  __shared__ float hs[HDIM];
  hs[threadIdx.x] = hp[b * HDIM + threadIdx.x];
  hs[threadIdx.x + 256] = hp[b * HDIM + threadIdx.x + 256];
  __syncthreads();
  const float4* wr = (const float4*)(Wa + (size_t)o * HDIM);
  float acc = 0.f;
#pragma unroll 8
  for (int i = 0; i < HDIM / 4; ++i) {
    float4 v = wr[i];
    acc += v.x * hs[i * 4 + 0] + v.y * hs[i * 4 + 1] + v.z * hs[i * 4 + 2] + v.w * hs[i * 4 + 3];
  }
  q[b * HDIM + o] = acc + Wab[o] + Uab[o];
}

__global__ __launch_bounds__(512, 4) void k_scores_ctx(
    const float* __restrict__ xref, const unsigned short* __restrict__ uab,
    const float* __restrict__ q, const float* __restrict__ va,
    float* __restrict__ mArr, float* __restrict__ lArr, float* __restrict__ cpart) {
  int chunk = blockIdx.x;
  int b = blockIdx.y;
  int tid = threadIdx.x;
  int l = tid & 63;
  int w = tid >> 6;          // 0..7, wave owns 64 rows x 64 cols
  int c = l & 15, g4 = l >> 4;

  // bf16 tile; logical byte (row,kb) stored at row*1024 + (kb ^ ((row&7)<<4))
  __shared__ __align__(16) unsigned short As[BM * HDIM];  // 64 KB
  __shared__ float sc[BM];
  __shared__ float pl[BM];

  f32x4 acc[4][4];
#pragma unroll
  for (int m = 0; m < 4; ++m)
#pragma unroll
    for (int n = 0; n < 4; ++n) acc[m][n] = f32x4{0.f, 0.f, 0.f, 0.f};

  const float* xb = xref + ((size_t)b * S_LEN + (size_t)chunk * BM) * HDIM;

  // staging: thread -> row = tid>>3 (8 lanes/row); per p-chunk the thread
  // covers 8 f32 (16 bf16 B) at kb = (tid&7)*16 + p*128.
  // Consecutive-8-lane groups have constant p/base and row&7 = 0..7 ->
  // slot = ((tid&7)*16 ^ ((row&7)<<4)) is a bijection per group: conflict-free.
  int srow = tid >> 3, skq = tid & 7;
  char* wb = (char*)&As[0] + srow * 1024 + ((skq * 16) ^ ((srow & 7) << 4));
  const float* sb = xb + (size_t)srow * HDIM + skq * 8;

  float4 a0, a1, a2, a3, a4, a5, a6, a7;

#define LD2(va, vb, p)                                                         \
  {                                                                            \
    va = *(const float4*)(sb + (p) * 64);                                      \
    vb = *(const float4*)(sb + (p) * 64 + 4);                                  \
  }

#define WR1(va, vb, p)                                                         \
  {                                                                            \
    union { __hip_bfloat162 h[4]; ushort8 s; } u_;                             \
    u_.h[0] = __float22bfloat162_rn(make_float2(va.x, va.y));                  \
    u_.h[1] = __float22bfloat162_rn(make_float2(va.z, va.w));                  \
    u_.h[2] = __float22bfloat162_rn(make_float2(vb.x, vb.y));                  \
    u_.h[3] = __float22bfloat162_rn(make_float2(vb.z, vb.w));                  \
    *(ushort8*)(wb + (p) * 128) = u_.s;                                        \
  }

  // 16-MFMA cluster for k-tile kt (wave cols w*64..w*64+63)
#define CLUSTER(kt)                                                            \
  {                                                                            \
    short8 afr_[4], bfr_[4];                                                   \
    _Pragma("unroll")                                                          \
    for (int n = 0; n < 4; ++n) {                                              \
      int ct = w * 4 + n;                                                      \
      bfr_[n] = *(const short8*)(uab + (((size_t)(ct * 16 + (kt)) * 64 + l) * 8)); \
    }                                                                          \
    _Pragma("unroll")                                                          \
    for (int m = 0; m < 4; ++m) {                                              \
      int row = m * 16 + (l & 15);                                             \
      int kb = ((kt) * 64 + (l >> 4) * 16) ^ ((row & 7) << 4);                 \
      afr_[m] = *(const short8*)((const char*)&As[0] + row * 1024 + kb);       \
    }                                                                          \
    __builtin_amdgcn_s_setprio(1);                                             \
    _Pragma("unroll")                                                          \
    for (int m = 0; m < 4; ++m)                                                \
      _Pragma("unroll")                                                        \
      for (int n = 0; n < 4; ++n)                                              \
        acc[m][n] = __builtin_amdgcn_mfma_f32_16x16x32_bf16(afr_[m], bfr_[n],  \
                                                            acc[m][n], 0, 0, 0); \
    __builtin_amdgcn_s_setprio(0);                                             \
  }

  // stage the full 64x512 tile: 2 load batches (32 regs), 2 latency waits
  LD2(a0, a1, 0) LD2(a2, a3, 1) LD2(a4, a5, 2) LD2(a6, a7, 3)
  WR1(a0, a1, 0) WR1(a2, a3, 1) WR1(a4, a5, 2) WR1(a6, a7, 3)
  LD2(a0, a1, 4) LD2(a2, a3, 5) LD2(a4, a5, 6) LD2(a6, a7, 7)
  WR1(a0, a1, 4) WR1(a2, a3, 5) WR1(a4, a5, 6) WR1(a6, a7, 7)
  if (tid < BM) sc[tid] = 0.f;
  __syncthreads();

  CLUSTER(0)  CLUSTER(1)  CLUSTER(2)  CLUSTER(3)
  CLUSTER(4)  CLUSTER(5)  CLUSTER(6)  CLUSTER(7)
  CLUSTER(8)  CLUSTER(9)  CLUSTER(10) CLUSTER(11)
  CLUSTER(12) CLUSTER(13)

  // q/Va loads hoisted under the last two clusters
  float qf[4], vf[4];
#pragma unroll
  for (int n = 0; n < 4; ++n) {
    int o = w * 64 + n * 16 + c;
    qf[n] = q[b * HDIM + o];
    vf[n] = va[o];
  }
  CLUSTER(14) CLUSTER(15)

  // scores[row] = sum_o tanh(acc + q[o]) * Va[o]
#pragma unroll
  for (int m = 0; m < 4; ++m) {
#pragma unroll
    for (int r = 0; r < 4; ++r) {
      float sum = 0.f;
#pragma unroll
      for (int n = 0; n < 4; ++n) sum += fast_tanh(acc[m][n][r] + qf[n]) * vf[n];
      sum += __shfl_xor(sum, 1);
      sum += __shfl_xor(sum, 2);
      sum += __shfl_xor(sum, 4);
      sum += __shfl_xor(sum, 8);
      if (c == 0) atomicAdd(&sc[m * 16 + g4 * 4 + r], sum);
    }
  }
  __syncthreads();

  // softmax over the 64 local rows (each wave computes identically)
  float M = sc[l];
#pragma unroll
  for (int off = 32; off >= 1; off >>= 1) M = fmaxf(M, __shfl_xor(M, off));
  float pp = __expf(sc[l] - M);
  float lsum = pp;
#pragma unroll
  for (int off = 32; off >= 1; off >>= 1) lsum += __shfl_xor(lsum, off);
  if (tid < BM) pl[tid] = pp;
  if (tid == 0) {
    mArr[b * NCHUNK + chunk] = M;
    lArr[b * NCHUNK + chunk] = lsum;
  }
  __syncthreads();

  // partial context from the bf16 LDS tile: thread = one of 512 cols
  {
    int h2 = tid * 2;  // logical kbyte of this col
    const char* base_ = (const char*)&As[0];
    float cacc = 0.f;
#pragma unroll 8
    for (int r = 0; r < BM; ++r) {
      int byte = r * 1024 + (h2 ^ ((r & 7) << 4));
      cacc += pl[r] * bf2f(*(const unsigned short*)(base_ + byte));
    }
    cpart[((size_t)b * NCHUNK + chunk) * HDIM + tid] = cacc;
  }
#undef LD2
#undef WR1
#undef CLUSTER
}

__global__ __launch_bounds__(512) void k_combine(const float* __restrict__ mArr,
                                                 const float* __restrict__ lArr,
                                                 const float* __restrict__ cpart,
                                                 float* __restrict__ ctx,
                                                 float* __restrict__ out_ctx) {
  int b = blockIdx.x, t = threadIdx.x;
  __shared__ float wf[NCHUNK];
  __shared__ float dinv;
  if (t == 0) {
    float M = mArr[b * NCHUNK];
    for (int i = 1; i < NCHUNK; ++i) M = fmaxf(M, mArr[b * NCHUNK + i]);
    float den = 0.f;
    for (int i = 0; i < NCHUNK; ++i) {
      float f = __expf(mArr[b * NCHUNK + i] - M);
      wf[i] = f;
      den += f * lArr[b * NCHUNK + i];
    }
    dinv = 1.0f / den;
  }
  __syncthreads();
  float s = 0.f;
#pragma unroll
  for (int i = 0; i < NCHUNK; ++i) s += wf[i] * cpart[((size_t)b * NCHUNK + i) * HDIM + t];
  float c = s * dinv;
  ctx[b * HDIM + t] = c;
  out_ctx[b * HDIM + t] = c;
}

__global__ __launch_bounds__(256) void k_rnn(const float* __restrict__ xt,
                                             const float* __restrict__ ctx,
                                             const float* __restrict__ hp,
                                             const float* __restrict__ Wih,
                                             const float* __restrict__ Wihb,
                                             const float* __restrict__ Whh,
                                             const float* __restrict__ Whhb,
                                             float* __restrict__ hout) {
  int b = blockIdx.x, oh = blockIdx.y;
  int o = oh * 256 + threadIdx.x;
  __shared__ float xs[EDIM], cs[HDIM], hs[HDIM];
  xs[threadIdx.x] = xt[b * EDIM + threadIdx.x];
  xs[threadIdx.x + 256] = xt[b * EDIM + threadIdx.x + 256];
  cs[threadIdx.x] = ctx[b * HDIM + threadIdx.x];
  cs[threadIdx.x + 256] = ctx[b * HDIM + threadIdx.x + 256];
  hs[threadIdx.x] = hp[b * HDIM + threadIdx.x];
  hs[threadIdx.x + 256] = hp[b * HDIM + threadIdx.x + 256];
  __syncthreads();
  const float4* wi = (const float4*)(Wih + (size_t)o * (EDIM + HDIM));
  float acc = Wihb[o] + Whhb[o];
#pragma unroll 8
  for (int i = 0; i < EDIM / 4; ++i) {
    float4 v = wi[i];
    acc += v.x * xs[i * 4] + v.y * xs[i * 4 + 1] + v.z * xs[i * 4 + 2] + v.w * xs[i * 4 + 3];
  }
  const float4* wi2 = wi + EDIM / 4;
#pragma unroll 8
  for (int i = 0; i < HDIM / 4; ++i) {
    float4 v = wi2[i];
    acc += v.x * cs[i * 4] + v.y * cs[i * 4 + 1] + v.z * cs[i * 4 + 2] + v.w * cs[i * 4 + 3];
  }
  const float4* wh = (const float4*)(Whh + (size_t)o * HDIM);
#pragma unroll 8
  for (int i = 0; i < HDIM / 4; ++i) {
    float4 v = wh[i];
    acc += v.x * hs[i * 4] + v.y * hs[i * 4 + 1] + v.z * hs[i * 4 + 2] + v.w * hs[i * 4 + 3];
  }
  hout[b * HDIM + o] = tanhf(acc);
}

extern "C" void kernel_launch(void* const* d_in, const int* in_sizes, int n_in,
                              void* d_out, int out_size, void* d_ws, size_t ws_size,
                              hipStream_t stream) {
  const float* x_t    = (const float*)d_in[0];
  const float* x_ref  = (const float*)d_in[1];
  const float* h_prev = (const float*)d_in[2];
  const float* Wa_w   = (const float*)d_in[3];
  const float* Wa_b   = (const float*)d_in[4];
  const float* Ua_w   = (const float*)d_in[5];
  const float* Ua_b   = (const float*)d_in[6];
  const float* Va_w   = (const float*)d_in[7];
  // d_in[8] = Va_b: softmax-invariant, skipped.
  const float* Wih_w  = (const float*)d_in[9];
  const float* Wih_b  = (const float*)d_in[10];
  const float* Whh_w  = (const float*)d_in[11];
  const float* Whh_b  = (const float*)d_in[12];

  char* ws = (char*)d_ws;
  unsigned short* ua_fr = (unsigned short*)ws;   // 512 KB fragment-layout Ua
  float* q     = (float*)(ws + 524288);          // 256 KB
  float* mArr  = (float*)(ws + 786432);          // 16 KB
  float* lArr  = (float*)(ws + 802816);          // 16 KB
  float* cpart = (float*)(ws + 819200);          // 8 MB
  float* ctx   = (float*)(ws + 9207808);         // 256 KB

  float* h_out   = (float*)d_out;
  float* ctx_out = h_out + BDIM * HDIM;

  k_cvt_b<<<dim3(128), dim3(256), 0, stream>>>(Ua_w, ua_fr);
  k_q<<<dim3(BDIM, 2), dim3(256), 0, stream>>>(h_prev, Wa_w, Wa_b, Ua_b, q);
  k_scores_ctx<<<dim3(NCHUNK, BDIM), dim3(512), 0, stream>>>(x_ref, ua_fr, q, Va_w, mArr, lArr, cpart);
  k_combine<<<dim3(BDIM), dim3(512), 0, stream>>>(mArr, lArr, cpart, ctx, ctx_out);
  k_rnn<<<dim3(BDIM, 2), dim3(256), 0, stream>>>(x_t, ctx, h_prev, Wih_w, Wih_b, Whh_w, Whh_b, h_out);
}